// Round 9
// baseline (106.210 us; speedup 1.0000x reference)
//
#include <hip/hip_runtime.h>
#include <hip/hip_bf16.h>
#include <math.h>

#define D 256
#define HID 16
#define CAP 96
#define TBM 16

typedef __attribute__((ext_vector_type(8))) short bf16x8;
typedef __attribute__((ext_vector_type(4))) float f32x4;

__device__ __forceinline__ ushort f2b(float x){
  uint u = __float_as_uint(x);
  u = u + 0x7FFFu + ((u >> 16) & 1u);   // round-to-nearest-even
  return (ushort)(u >> 16);
}
__device__ __forceinline__ float b2f(ushort u){ return __uint_as_float(((uint)u) << 16); }

// ---- prep: h->bf16 convert + pack 6 weight matrices + zero cur ----
// packed B layout: frag(nt,kt,lane,i) at [((nt*8+kt)*64+lane)*8+i]
// = W[kt*32 + (lane>>4)*8 + i][nt*16 + (lane&15)]
__global__ void prep_kernel(const float* h, ushort* Hbf, int NC,
                            const float* Wm1, const float* Wm2,
                            const float* Wu1, const float* Wu2,
                            ushort* pAll, int* cur, int N){
  int total = NC + 6 * 65536 + N;
  for (int idx = blockIdx.x * blockDim.x + threadIdx.x; idx < total;
       idx += gridDim.x * blockDim.x){
    if (idx < NC){ Hbf[idx] = f2b(h[idx]); continue; }
    int q = idx - NC;
    if (q < 6 * 65536){
      int mat = q >> 16, p = q & 65535;
      int i = p & 7, l = (p >> 3) & 63, kt = (p >> 9) & 7, nt = p >> 12;
      int k = kt * 32 + ((l >> 4) * 8) + i;
      int n = nt * 16 + (l & 15);
      const float* src;
      switch (mat){
        case 0: src = Wm1 + (size_t)k * 256 + n; break;            // Wm1a
        case 1: src = Wm1 + (size_t)(256 + k) * 256 + n; break;    // Wm1b
        case 2: src = Wm2 + (size_t)k * 256 + n; break;
        case 3: src = Wu1 + (size_t)k * 256 + n; break;            // Wu1a
        case 4: src = Wu1 + (size_t)(256 + k) * 256 + n; break;    // Wu1b
        default: src = Wu2 + (size_t)k * 256 + n; break;
      }
      pAll[q] = f2b(*src);
      continue;
    }
    q -= 6 * 65536;
    if (q < N) cur[q] = 0;
  }
}

// stage one 32KB packed-B chunk into LDS (256-thread blocks)
__device__ __forceinline__ void stage_chunk(const ushort* src, ushort* lds, int tid){
  #pragma unroll
  for (int c = 0; c < 8; ++c)
    __builtin_amdgcn_global_load_lds(
      (const __attribute__((address_space(1))) uint*)(src + tid * 8 + c * 2048),
      (__attribute__((address_space(3))) uint*)(lds + tid * 8 + c * 2048), 16, 0, 0);
}

__device__ __forceinline__ void gemm_compute(const ushort* A, int r0, int r1, int kl,
                                             const ushort* lds, int lane,
                                             f32x4 acc[2][4]){
  const ushort* ap0 = A + (size_t)r0 * 256 + kl;
  const ushort* ap1 = A + (size_t)r1 * 256 + kl;
  #pragma unroll
  for (int kt = 0; kt < 8; ++kt){
    bf16x8 b0 = *(const bf16x8*)(lds + ((size_t)(0 * 8 + kt) * 64 + lane) * 8);
    bf16x8 b1 = *(const bf16x8*)(lds + ((size_t)(1 * 8 + kt) * 64 + lane) * 8);
    bf16x8 b2 = *(const bf16x8*)(lds + ((size_t)(2 * 8 + kt) * 64 + lane) * 8);
    bf16x8 b3 = *(const bf16x8*)(lds + ((size_t)(3 * 8 + kt) * 64 + lane) * 8);
    bf16x8 a0 = *(const bf16x8*)(ap0 + kt * 32);
    bf16x8 a1 = *(const bf16x8*)(ap1 + kt * 32);
    acc[0][0] = __builtin_amdgcn_mfma_f32_16x16x32_bf16(a0, b0, acc[0][0], 0, 0, 0);
    acc[0][1] = __builtin_amdgcn_mfma_f32_16x16x32_bf16(a0, b1, acc[0][1], 0, 0, 0);
    acc[0][2] = __builtin_amdgcn_mfma_f32_16x16x32_bf16(a0, b2, acc[0][2], 0, 0, 0);
    acc[0][3] = __builtin_amdgcn_mfma_f32_16x16x32_bf16(a0, b3, acc[0][3], 0, 0, 0);
    acc[1][0] = __builtin_amdgcn_mfma_f32_16x16x32_bf16(a1, b0, acc[1][0], 0, 0, 0);
    acc[1][1] = __builtin_amdgcn_mfma_f32_16x16x32_bf16(a1, b1, acc[1][1], 0, 0, 0);
    acc[1][2] = __builtin_amdgcn_mfma_f32_16x16x32_bf16(a1, b2, acc[1][2], 0, 0, 0);
    acc[1][3] = __builtin_amdgcn_mfma_f32_16x16x32_bf16(a1, b3, acc[1][3], 0, 0, 0);
  }
}

// ---- G1 + fill fused: [P1|P2a|P2b] = H @ [Wm1a|Wm1b] (split f32|bf16-halves),
// then edge bucketing with inline attention MLP.
__global__ __launch_bounds__(256) void g1f_kernel(
    const ushort* __restrict__ Hbf, const ushort* __restrict__ B,
    float* __restrict__ P1, ushort* __restrict__ P2a, ushort* __restrict__ P2b,
    const int* __restrict__ ei, const int* __restrict__ val,
    const float* __restrict__ Wa1, const float* __restrict__ ba1,
    const float* __restrict__ Wa2, const float* __restrict__ ba2,
    int* __restrict__ cur, uint2* __restrict__ elist,
    int M, int E, int ntiles){
  extern __shared__ ushort lds[];
  int tid = threadIdx.x;
  for (int t = blockIdx.x; t < ntiles; t += gridDim.x){
    int bn = t % 8, bm = t / 8;
    stage_chunk(B + (size_t)bn * 16384, lds, tid);
    __syncthreads();
    int wave = tid >> 6, lane = tid & 63;
    int rbase = bm * 128 + wave * 32;
    int r0 = min(rbase + (lane & 15), M - 1);
    int r1 = min(rbase + 16 + (lane & 15), M - 1);
    int kl = (lane >> 4) * 8;
    f32x4 zero = {0.f, 0.f, 0.f, 0.f};
    f32x4 acc[2][4];
    #pragma unroll
    for (int x = 0; x < 2; ++x)
      #pragma unroll
      for (int y = 0; y < 4; ++y) acc[x][y] = zero;
    gemm_compute(Hbf, r0, r1, kl, lds, lane, acc);
    int coll = lane & 15, rl = (lane >> 4) * 4;
    #pragma unroll
    for (int rt = 0; rt < 2; ++rt){
      #pragma unroll
      for (int n = 0; n < 4; ++n){
        int cg = bn * 64 + n * 16 + coll;
        #pragma unroll
        for (int j = 0; j < 4; ++j){
          int r = rbase + rt * 16 + rl + j;
          if (r < M){
            float v = acc[rt][n][j];
            if (cg < 256) P1[(size_t)r * 256 + cg] = v;
            else {
              int f = cg - 256;
              ushort vb = f2b(v);
              if (f < 128) P2a[(size_t)r * 128 + f] = vb;
              else         P2b[(size_t)r * 128 + (f - 128)] = vb;
            }
          }
        }
      }
    }
    __syncthreads();
  }
  // fill: bucket edges with inline attention MLP
  for (int e = blockIdx.x * 256 + tid; e < E; e += gridDim.x * 256){
    int r = ei[e], c = ei[E + e];
    int vri = val[r], vci = val[c];
    float vr = (float)vri, vc = (float)vci;
    float s = ba2[0];
    #pragma unroll
    for (int j = 0; j < HID; ++j){
      float hj = fmaxf(vr * Wa1[j] + vc * Wa1[HID + j] + ba1[j], 0.f);
      s += hj * Wa2[j];
    }
    float att = 1.f / (1.f + expf(-s));
    int pos = atomicAdd(&cur[r], 1);
    if (pos < CAP)
      elist[(size_t)r * CAP + pos] =
          make_uint2((uint)c | ((uint)vci << 16), __float_as_uint(att));
  }
}

// one gather pass over a 128-feature half of P2 (2.5MB -> L2-resident).
// 2 edges per step: lanes 0-31 = edge e+0, lanes 32-63 = edge e+1, same features.
// fo = (lane&31)*4 elements into the half. Returns per-lane partial sums
// (pre-swap); satt_io accumulates per-lane att sum.
__device__ __forceinline__ f32x4 gather_pass(
    const ushort* __restrict__ P2h, const uint2* __restrict__ el,
    int dg, int sub, int fo,
    float bx, float by, float bz, float bw,
    float wvx, float wvy, float wvz, float wvw,
    float& satt_io){
  float ax = 0.f, ay = 0.f, az = 0.f, aw = 0.f, satt = 0.f;
  int e = 0;
  for (; e + 8 <= dg; e += 8){          // 4 pairs = 8 edges, ILP-4 loads
    uint2 qs[4];
    #pragma unroll
    for (int k = 0; k < 4; ++k) qs[k] = el[e + 2 * k + sub];
    ushort4 vs[4];
    #pragma unroll
    for (int k = 0; k < 4; ++k)
      vs[k] = *(const ushort4*)(P2h + (size_t)(qs[k].x & 0xFFFFu) * 128 + fo);
    #pragma unroll
    for (int k = 0; k < 4; ++k){
      float vck = (float)(qs[k].x >> 16), atk = __uint_as_float(qs[k].y);
      ax += atk * fmaxf(bx + b2f(vs[k].x) + vck * wvx, 0.f);
      ay += atk * fmaxf(by + b2f(vs[k].y) + vck * wvy, 0.f);
      az += atk * fmaxf(bz + b2f(vs[k].z) + vck * wvz, 0.f);
      aw += atk * fmaxf(bw + b2f(vs[k].w) + vck * wvw, 0.f);
      satt += atk;
    }
  }
  for (; e < dg; e += 2){
    int ei = e + sub;
    uint2 q0 = (ei < dg) ? el[ei] : make_uint2(0u, 0u);   // att bits 0 -> 0.0f
    ushort4 v0 = *(const ushort4*)(P2h + (size_t)(q0.x & 0xFFFFu) * 128 + fo);
    float vc0 = (float)(q0.x >> 16), at0 = __uint_as_float(q0.y);
    ax += at0 * fmaxf(bx + b2f(v0.x) + vc0 * wvx, 0.f);
    ay += at0 * fmaxf(by + b2f(v0.y) + vc0 * wvy, 0.f);
    az += at0 * fmaxf(bz + b2f(v0.z) + vc0 * wvz, 0.f);
    aw += at0 * fmaxf(bw + b2f(v0.w) + vc0 * wvw, 0.f);
    satt += at0;
  }
  f32x4 r = {ax, ay, az, aw};
  satt_io += satt;
  return r;
}

// ---- fused tail v4: 512 threads / 8 waves, TBM=16 rows. Phase A gathers the
// two P2 halves in two passes (each half L2-resident), merging via shfl_xor(32).
// Then the 3-layer row-local GEMM chain (wave owns 2 column-tiles).
__global__ __launch_bounds__(512) void fused_tail_kernel(
    const float* __restrict__ P1,
    const ushort* __restrict__ P2a, const ushort* __restrict__ P2b,
    const int* __restrict__ cur, const uint2* __restrict__ elist,
    const int* __restrict__ val, const float* __restrict__ Wm1,
    const float* __restrict__ bm1, const ushort* __restrict__ Hbf,
    const ushort* __restrict__ pWm2, const ushort* __restrict__ pWu1a,
    const ushort* __restrict__ pWu1b, const ushort* __restrict__ pWu2,
    const float* __restrict__ bm2, const float* __restrict__ bu1,
    const float* __restrict__ bu2, const float* __restrict__ h,
    float* __restrict__ out, int M){
  __shared__ ushort qt[TBM * 256];    // 8KB swizzled Q tile; reused as T tile
  __shared__ ushort hag[TBM * 256];   // 8KB swizzled Hagg tile
  __shared__ float Sl[TBM];

  int tid = threadIdx.x, w = tid >> 6, lane = tid & 63;
  int row0 = blockIdx.x * TBM;
  int sub = lane >> 5;                // which edge of the pair this lane handles
  int fh = (lane & 31) * 4;           // feature offset within a 128-half

  // ---- phase A ----
  {
    const float* wvr = Wm1 + (size_t)512 * 256;
    const float* wvc = Wm1 + (size_t)513 * 256;
    #pragma unroll 1
    for (int qq = 0; qq < 2; ++qq){
      int rl = w * 2 + qq;
      int r = row0 + rl;
      f32x4 qlo = {0.f,0.f,0.f,0.f}, qhi = {0.f,0.f,0.f,0.f};
      float satt = 0.f;
      if (r < M){
        int dg = min(cur[r], CAP);
        const uint2* el = elist + (size_t)r * CAP;
        float vrf = (float)val[r];
        // pass 1: features [0,128)
        {
          int f = fh;
          float4 p1 = *(const float4*)(P1 + (size_t)r * D + f);
          float4 wr4 = *(const float4*)(wvr + f);
          float4 wv  = *(const float4*)(wvc + f);
          float4 bb  = *(const float4*)(bm1 + f);
          qlo = gather_pass(P2a, el, dg, sub, fh,
                            p1.x + vrf * wr4.x + bb.x, p1.y + vrf * wr4.y + bb.y,
                            p1.z + vrf * wr4.z + bb.z, p1.w + vrf * wr4.w + bb.w,
                            wv.x, wv.y, wv.z, wv.w, satt);
          qlo[0] += __shfl_xor(qlo[0], 32);
          qlo[1] += __shfl_xor(qlo[1], 32);
          qlo[2] += __shfl_xor(qlo[2], 32);
          qlo[3] += __shfl_xor(qlo[3], 32);
          satt   += __shfl_xor(satt,   32);
        }
        // pass 2: features [128,256)
        {
          int f = fh + 128;
          float4 p1 = *(const float4*)(P1 + (size_t)r * D + f);
          float4 wr4 = *(const float4*)(wvr + f);
          float4 wv  = *(const float4*)(wvc + f);
          float4 bb  = *(const float4*)(bm1 + f);
          float dead = 0.f;
          qhi = gather_pass(P2b, el, dg, sub, fh,
                            p1.x + vrf * wr4.x + bb.x, p1.y + vrf * wr4.y + bb.y,
                            p1.z + vrf * wr4.z + bb.z, p1.w + vrf * wr4.w + bb.w,
                            wv.x, wv.y, wv.z, wv.w, dead);
          qhi[0] += __shfl_xor(qhi[0], 32);
          qhi[1] += __shfl_xor(qhi[1], 32);
          qhi[2] += __shfl_xor(qhi[2], 32);
          qhi[3] += __shfl_xor(qhi[3], 32);
        }
      }
      // lane<32 -> features lane*4 (pass1); lane>=32 -> features lane*4 (pass2)
      f32x4 qsel = (lane < 32) ? qlo : qhi;
      ushort4 qo; qo.x = f2b(qsel[0]); qo.y = f2b(qsel[1]);
      qo.z = f2b(qsel[2]); qo.w = f2b(qsel[3]);
      *(ushort4*)((char*)qt + rl * 512 + ((lane * 8) ^ ((rl & 7) << 4))) = qo;
      if (lane == 0) Sl[rl] = satt;
    }
  }
  __syncthreads();

  // ---- GEMM chain: wave w owns 2 column-tiles (32 cols) x 16 rows ----
  int nt0 = w * 2;
  int fr = lane & 15, kl = (lane >> 4) * 8, rq = (lane >> 4) * 4;
  int swA = (fr & 7) << 4;
  const char* qbase = (const char*)qt + fr * 512;
  const char* hbase = (const char*)hag + fr * 512;
  f32x4 zero = {0.f, 0.f, 0.f, 0.f};

  // L1: hag = qt @ Wm2 + S*bm2
  {
    f32x4 acc[2] = {zero, zero};
    #pragma unroll
    for (int kt = 0; kt < 8; ++kt){
      bf16x8 a = *(const bf16x8*)(qbase + (((kl + kt * 32) * 2) ^ swA));
      #pragma unroll
      for (int n = 0; n < 2; ++n){
        bf16x8 b = *(const bf16x8*)(pWm2 + (size_t)(nt0 + n) * 4096 + kt * 512 + lane * 8);
        acc[n] = __builtin_amdgcn_mfma_f32_16x16x32_bf16(a, b, acc[n], 0, 0, 0);
      }
    }
    #pragma unroll
    for (int n = 0; n < 2; ++n){
      int cc = (nt0 + n) * 16 + fr;
      float bv = bm2[cc];
      #pragma unroll
      for (int j = 0; j < 4; ++j){
        int rr = rq + j;
        float v = acc[n][j] + Sl[rr] * bv;
        *(ushort*)((char*)hag + rr * 512 + ((cc * 2) ^ ((rr & 7) << 4))) = f2b(v);
      }
    }
  }
  __syncthreads();

  // L2: tt(=qt) = relu(Hbf @ Wu1a + hag @ Wu1b + bu1)
  {
    f32x4 acc[2] = {zero, zero};
    const ushort* ap_h = Hbf + (size_t)min(row0 + fr, M - 1) * 256 + kl;
    #pragma unroll
    for (int kt = 0; kt < 8; ++kt){
      bf16x8 a = *(const bf16x8*)(ap_h + kt * 32);
      #pragma unroll
      for (int n = 0; n < 2; ++n){
        bf16x8 b = *(const bf16x8*)(pWu1a + (size_t)(nt0 + n) * 4096 + kt * 512 + lane * 8);
        acc[n] = __builtin_amdgcn_mfma_f32_16x16x32_bf16(a, b, acc[n], 0, 0, 0);
      }
    }
    #pragma unroll
    for (int kt = 0; kt < 8; ++kt){
      bf16x8 a = *(const bf16x8*)(hbase + (((kl + kt * 32) * 2) ^ swA));
      #pragma unroll
      for (int n = 0; n < 2; ++n){
        bf16x8 b = *(const bf16x8*)(pWu1b + (size_t)(nt0 + n) * 4096 + kt * 512 + lane * 8);
        acc[n] = __builtin_amdgcn_mfma_f32_16x16x32_bf16(a, b, acc[n], 0, 0, 0);
      }
    }
    __syncthreads();                 // everyone done reading qt (L1) -> reuse as tt
    #pragma unroll
    for (int n = 0; n < 2; ++n){
      int cc = (nt0 + n) * 16 + fr;
      float bv = bu1[cc];
      #pragma unroll
      for (int j = 0; j < 4; ++j){
        int rr = rq + j;
        float v = fmaxf(acc[n][j] + bv, 0.f);
        *(ushort*)((char*)qt + rr * 512 + ((cc * 2) ^ ((rr & 7) << 4))) = f2b(v);
      }
    }
  }
  __syncthreads();

  // L3: out = h + tt @ Wu2 + bu2   (tt lives in qt)
  {
    f32x4 acc[2] = {zero, zero};
    #pragma unroll
    for (int kt = 0; kt < 8; ++kt){
      bf16x8 a = *(const bf16x8*)(qbase + (((kl + kt * 32) * 2) ^ swA));
      #pragma unroll
      for (int n = 0; n < 2; ++n){
        bf16x8 b = *(const bf16x8*)(pWu2 + (size_t)(nt0 + n) * 4096 + kt * 512 + lane * 8);
        acc[n] = __builtin_amdgcn_mfma_f32_16x16x32_bf16(a, b, acc[n], 0, 0, 0);
      }
    }
    #pragma unroll
    for (int n = 0; n < 2; ++n){
      int cc = (nt0 + n) * 16 + fr;
      float bv = bu2[cc];
      #pragma unroll
      for (int j = 0; j < 4; ++j){
        int gr = row0 + rq + j;
        if (gr < M)
          out[(size_t)gr * 256 + cc] = acc[n][j] + bv + h[(size_t)gr * 256 + cc];
      }
    }
  }
}

extern "C" void kernel_launch(void* const* d_in, const int* in_sizes, int n_in,
                              void* d_out, int out_size, void* d_ws, size_t ws_size,
                              hipStream_t stream){
  const float* h   = (const float*)d_in[0];
  const int*   ei  = (const int*)d_in[1];
  const int*   val = (const int*)d_in[3];
  const float* Wm1 = (const float*)d_in[4];
  const float* bm1 = (const float*)d_in[5];
  const float* Wm2 = (const float*)d_in[6];
  const float* bm2 = (const float*)d_in[7];
  const float* Wu1 = (const float*)d_in[8];
  const float* bu1 = (const float*)d_in[9];
  const float* Wu2 = (const float*)d_in[10];
  const float* bu2 = (const float*)d_in[11];
  const float* Wa1 = (const float*)d_in[12];
  const float* ba1 = (const float*)d_in[13];
  const float* Wa2 = (const float*)d_in[14];
  const float* ba2 = (const float*)d_in[15];
  int N = in_sizes[0] / D;
  int E = in_sizes[1] / 2;
  float* out = (float*)d_out;

  char* ws = (char*)d_ws;
  size_t o = 0;
  auto alloc = [&](size_t bytes)->char*{
    char* p = ws + o; o += (bytes + 255) & ~(size_t)255; return p;
  };
  float*  P1    = (float*) alloc((size_t)N * D * 4);
  ushort* P2a   = (ushort*)alloc((size_t)N * 128 * 2);   // features 0-127
  ushort* P2b   = (ushort*)alloc((size_t)N * 128 * 2);   // features 128-255
  ushort* Hbf   = (ushort*)alloc((size_t)N * D * 2);
  int*    cur   = (int*)   alloc((size_t)N * 4);
  uint2*  elist = (uint2*) alloc((size_t)N * CAP * 8);
  ushort* pAll  = (ushort*)alloc((size_t)6 * 65536 * 2);
  ushort* pWm1c = pAll;               // [Wm1a|Wm1b] (N=512 cat)
  ushort* pWm2  = pAll + 2 * 65536;
  ushort* pWu1a = pAll + 3 * 65536;
  ushort* pWu1b = pAll + 4 * 65536;
  ushort* pWu2  = pAll + 5 * 65536;

  int NC = N * D;
  prep_kernel<<<2048, 256, 0, stream>>>(h, Hbf, NC, Wm1, Wm2, Wu1, Wu2, pAll, cur, N);

  int mblocks = (N + 127) / 128;

  // D2: G1 (split P1|P2a|P2b) + edge bucketing
  g1f_kernel<<<1024, 256, 32768, stream>>>(
      Hbf, pWm1c, P1, P2a, P2b, ei, val, Wa1, ba1, Wa2, ba2, cur, elist,
      N, E, mblocks * 8);

  // D3: fused aggregation (half-split, L2-resident) + row-local 3-layer tail
  fused_tail_kernel<<<(N + TBM - 1) / TBM, 512, 0, stream>>>(
      P1, P2a, P2b, cur, elist, val, Wm1, bm1, Hbf,
      pWm2, pWu1a, pWu1b, pWu2, bm2, bu1, bu2, h, out, N);
}

// Round 11
// 90.292 us; speedup vs baseline: 1.1763x; 1.1763x over previous
//
#include <hip/hip_runtime.h>
#include <hip/hip_bf16.h>
#include <math.h>

#define D 256
#define HID 16
#define CAP 96
#define TBM 16

typedef __attribute__((ext_vector_type(8))) short bf16x8;
typedef __attribute__((ext_vector_type(4))) float f32x4;

__device__ __forceinline__ ushort f2b(float x){
  uint u = __float_as_uint(x);
  u = u + 0x7FFFu + ((u >> 16) & 1u);   // round-to-nearest-even
  return (ushort)(u >> 16);
}
__device__ __forceinline__ float b2f(ushort u){ return __uint_as_float(((uint)u) << 16); }

// ---- prep: h->bf16 convert + pack 6 weight matrices + zero cur ----
// packed B layout: frag(nt,kt,lane,i) at [((nt*8+kt)*64+lane)*8+i]
// = W[kt*32 + (lane>>4)*8 + i][nt*16 + (lane&15)]
__global__ void prep_kernel(const float* h, ushort* Hbf, int NC,
                            const float* Wm1, const float* Wm2,
                            const float* Wu1, const float* Wu2,
                            ushort* pAll, int* cur, int N){
  int total = NC + 6 * 65536 + N;
  for (int idx = blockIdx.x * blockDim.x + threadIdx.x; idx < total;
       idx += gridDim.x * blockDim.x){
    if (idx < NC){ Hbf[idx] = f2b(h[idx]); continue; }
    int q = idx - NC;
    if (q < 6 * 65536){
      int mat = q >> 16, p = q & 65535;
      int i = p & 7, l = (p >> 3) & 63, kt = (p >> 9) & 7, nt = p >> 12;
      int k = kt * 32 + ((l >> 4) * 8) + i;
      int n = nt * 16 + (l & 15);
      const float* src;
      switch (mat){
        case 0: src = Wm1 + (size_t)k * 256 + n; break;            // Wm1a
        case 1: src = Wm1 + (size_t)(256 + k) * 256 + n; break;    // Wm1b
        case 2: src = Wm2 + (size_t)k * 256 + n; break;
        case 3: src = Wu1 + (size_t)k * 256 + n; break;            // Wu1a
        case 4: src = Wu1 + (size_t)(256 + k) * 256 + n; break;    // Wu1b
        default: src = Wu2 + (size_t)k * 256 + n; break;
      }
      pAll[q] = f2b(*src);
      continue;
    }
    q -= 6 * 65536;
    if (q < N) cur[q] = 0;
  }
}

// stage one 32KB packed-B chunk into LDS (256-thread blocks)
__device__ __forceinline__ void stage_chunk(const ushort* src, ushort* lds, int tid){
  #pragma unroll
  for (int c = 0; c < 8; ++c)
    __builtin_amdgcn_global_load_lds(
      (const __attribute__((address_space(1))) uint*)(src + tid * 8 + c * 2048),
      (__attribute__((address_space(3))) uint*)(lds + tid * 8 + c * 2048), 16, 0, 0);
}

__device__ __forceinline__ void gemm_compute(const ushort* A, int r0, int r1, int kl,
                                             const ushort* lds, int lane,
                                             f32x4 acc[2][4]){
  const ushort* ap0 = A + (size_t)r0 * 256 + kl;
  const ushort* ap1 = A + (size_t)r1 * 256 + kl;
  #pragma unroll
  for (int kt = 0; kt < 8; ++kt){
    bf16x8 b0 = *(const bf16x8*)(lds + ((size_t)(0 * 8 + kt) * 64 + lane) * 8);
    bf16x8 b1 = *(const bf16x8*)(lds + ((size_t)(1 * 8 + kt) * 64 + lane) * 8);
    bf16x8 b2 = *(const bf16x8*)(lds + ((size_t)(2 * 8 + kt) * 64 + lane) * 8);
    bf16x8 b3 = *(const bf16x8*)(lds + ((size_t)(3 * 8 + kt) * 64 + lane) * 8);
    bf16x8 a0 = *(const bf16x8*)(ap0 + kt * 32);
    bf16x8 a1 = *(const bf16x8*)(ap1 + kt * 32);
    acc[0][0] = __builtin_amdgcn_mfma_f32_16x16x32_bf16(a0, b0, acc[0][0], 0, 0, 0);
    acc[0][1] = __builtin_amdgcn_mfma_f32_16x16x32_bf16(a0, b1, acc[0][1], 0, 0, 0);
    acc[0][2] = __builtin_amdgcn_mfma_f32_16x16x32_bf16(a0, b2, acc[0][2], 0, 0, 0);
    acc[0][3] = __builtin_amdgcn_mfma_f32_16x16x32_bf16(a0, b3, acc[0][3], 0, 0, 0);
    acc[1][0] = __builtin_amdgcn_mfma_f32_16x16x32_bf16(a1, b0, acc[1][0], 0, 0, 0);
    acc[1][1] = __builtin_amdgcn_mfma_f32_16x16x32_bf16(a1, b1, acc[1][1], 0, 0, 0);
    acc[1][2] = __builtin_amdgcn_mfma_f32_16x16x32_bf16(a1, b2, acc[1][2], 0, 0, 0);
    acc[1][3] = __builtin_amdgcn_mfma_f32_16x16x32_bf16(a1, b3, acc[1][3], 0, 0, 0);
  }
}

// ---- G1 + fill fused: [P1|P2] = H @ [Wm1a|Wm1b] (split f32|bf16), then edge bucketing.
__global__ __launch_bounds__(256) void g1f_kernel(
    const ushort* __restrict__ Hbf, const ushort* __restrict__ B,
    float* __restrict__ P1, ushort* __restrict__ P2,
    const int* __restrict__ ei, const int* __restrict__ val,
    const float* __restrict__ Wa1, const float* __restrict__ ba1,
    const float* __restrict__ Wa2, const float* __restrict__ ba2,
    int* __restrict__ cur, uint2* __restrict__ elist,
    int M, int E, int ntiles){
  extern __shared__ ushort lds[];
  int tid = threadIdx.x;
  for (int t = blockIdx.x; t < ntiles; t += gridDim.x){
    int bn = t % 8, bm = t / 8;
    stage_chunk(B + (size_t)bn * 16384, lds, tid);
    __syncthreads();
    int wave = tid >> 6, lane = tid & 63;
    int rbase = bm * 128 + wave * 32;
    int r0 = min(rbase + (lane & 15), M - 1);
    int r1 = min(rbase + 16 + (lane & 15), M - 1);
    int kl = (lane >> 4) * 8;
    f32x4 zero = {0.f, 0.f, 0.f, 0.f};
    f32x4 acc[2][4];
    #pragma unroll
    for (int x = 0; x < 2; ++x)
      #pragma unroll
      for (int y = 0; y < 4; ++y) acc[x][y] = zero;
    gemm_compute(Hbf, r0, r1, kl, lds, lane, acc);
    int coll = lane & 15, rl = (lane >> 4) * 4;
    #pragma unroll
    for (int rt = 0; rt < 2; ++rt){
      #pragma unroll
      for (int n = 0; n < 4; ++n){
        int cg = bn * 64 + n * 16 + coll;
        #pragma unroll
        for (int j = 0; j < 4; ++j){
          int r = rbase + rt * 16 + rl + j;
          if (r < M){
            float v = acc[rt][n][j];
            if (cg < 256) P1[(size_t)r * 256 + cg] = v;
            else P2[(size_t)r * 256 + (cg - 256)] = f2b(v);
          }
        }
      }
    }
    __syncthreads();
  }
  // fill: bucket edges with inline attention MLP
  for (int e = blockIdx.x * 256 + tid; e < E; e += gridDim.x * 256){
    int r = ei[e], c = ei[E + e];
    int vri = val[r], vci = val[c];
    float vr = (float)vri, vc = (float)vci;
    float s = ba2[0];
    #pragma unroll
    for (int j = 0; j < HID; ++j){
      float hj = fmaxf(vr * Wa1[j] + vc * Wa1[HID + j] + ba1[j], 0.f);
      s += hj * Wa2[j];
    }
    float att = 1.f / (1.f + expf(-s));
    int pos = atomicAdd(&cur[r], 1);
    if (pos < CAP)
      elist[(size_t)r * CAP + pos] =
          make_uint2((uint)c | ((uint)vci << 16), __float_as_uint(att));
  }
}

// ---- fused tail v2 (proven R7): 256 thr / 4 waves, TBM=16 rows/block,
// ~16.4KB LDS, no B staging (B frags read L2-direct from packed buffers).
// Phase A: per-wave 4-row gather (8-deep ILP). Then Q@Wm2 ->
// relu(H@Wu1a+Hagg@Wu1b) -> out = h + T@Wu2, Q/Hagg/T in swizzled LDS tiles.
__global__ __launch_bounds__(256) void fused_tail_kernel(
    const float* __restrict__ P1, const ushort* __restrict__ P2,
    const int* __restrict__ cur, const uint2* __restrict__ elist,
    const int* __restrict__ val, const float* __restrict__ Wm1,
    const float* __restrict__ bm1, const ushort* __restrict__ Hbf,
    const ushort* __restrict__ pWm2, const ushort* __restrict__ pWu1a,
    const ushort* __restrict__ pWu1b, const ushort* __restrict__ pWu2,
    const float* __restrict__ bm2, const float* __restrict__ bu1,
    const float* __restrict__ bu2, const float* __restrict__ h,
    float* __restrict__ out, int M){
  __shared__ ushort qt[TBM * 256];    // 8KB swizzled Q tile; reused as T tile
  __shared__ ushort hag[TBM * 256];   // 8KB swizzled Hagg tile
  __shared__ float Sl[TBM];

  int tid = threadIdx.x, w = tid >> 6, lane = tid & 63;
  int row0 = blockIdx.x * TBM;

  // ---- phase A: Q[r] = sum_e att*relu(P1[r]+P2[col]+vr*wvr+vc*wvc+bm1) ----
  {
    int f0 = lane * 4;
    const float* wvr = Wm1 + (size_t)512 * 256;
    const float* wvc = Wm1 + (size_t)513 * 256;
    float4 wr4 = *(const float4*)(wvr + f0);
    float4 wv  = *(const float4*)(wvc + f0);
    float4 bb  = *(const float4*)(bm1 + f0);
    #pragma unroll 1
    for (int qq = 0; qq < 4; ++qq){
      int rl = w * 4 + qq;
      int r = row0 + rl;
      float ax = 0.f, ay = 0.f, az = 0.f, aw = 0.f, satt = 0.f;
      if (r < M){
        float4 p1 = *(const float4*)(P1 + (size_t)r * D + f0);
        float vrf = (float)val[r];
        float bx = p1.x + vrf * wr4.x + bb.x;
        float by = p1.y + vrf * wr4.y + bb.y;
        float bz = p1.z + vrf * wr4.z + bb.z;
        float bw = p1.w + vrf * wr4.w + bb.w;
        int dg = min(cur[r], CAP);
        const uint2* el = elist + (size_t)r * CAP;
        int e = 0;
        for (; e + 8 <= dg; e += 8){        // 8-deep gather pipeline
          uint2 qs[8];
          #pragma unroll
          for (int k = 0; k < 8; ++k) qs[k] = el[e + k];
          ushort4 vs[8];
          #pragma unroll
          for (int k = 0; k < 8; ++k)
            vs[k] = *(const ushort4*)(P2 + (size_t)(qs[k].x & 0xFFFFu) * D + f0);
          #pragma unroll
          for (int k = 0; k < 8; ++k){
            float vck = (float)(qs[k].x >> 16), atk = __uint_as_float(qs[k].y);
            ax += atk * fmaxf(bx + b2f(vs[k].x) + vck * wv.x, 0.f);
            ay += atk * fmaxf(by + b2f(vs[k].y) + vck * wv.y, 0.f);
            az += atk * fmaxf(bz + b2f(vs[k].z) + vck * wv.z, 0.f);
            aw += atk * fmaxf(bw + b2f(vs[k].w) + vck * wv.w, 0.f);
            satt += atk;
          }
        }
        for (; e < dg; ++e){
          uint2 q0 = el[e];
          ushort4 v0 = *(const ushort4*)(P2 + (size_t)(q0.x & 0xFFFFu) * D + f0);
          float vc0 = (float)(q0.x >> 16), at0 = __uint_as_float(q0.y);
          ax += at0 * fmaxf(bx + b2f(v0.x) + vc0 * wv.x, 0.f);
          ay += at0 * fmaxf(by + b2f(v0.y) + vc0 * wv.y, 0.f);
          az += at0 * fmaxf(bz + b2f(v0.z) + vc0 * wv.z, 0.f);
          aw += at0 * fmaxf(bw + b2f(v0.w) + vc0 * wv.w, 0.f);
          satt += at0;
        }
      }
      ushort4 qo; qo.x = f2b(ax); qo.y = f2b(ay); qo.z = f2b(az); qo.w = f2b(aw);
      *(ushort4*)((char*)qt + rl * 512 + ((lane * 8) ^ ((rl & 7) << 4))) = qo;
      if (lane == 0) Sl[rl] = satt;
    }
  }
  __syncthreads();

  // ---- GEMM chain: wave w owns 4 column-tiles (64 cols) x 16 rows ----
  int nt0 = w * 4;
  int fr = lane & 15, kl = (lane >> 4) * 8, rq = (lane >> 4) * 4;
  int swA = (fr & 7) << 4;
  const char* qbase = (const char*)qt + fr * 512;
  const char* hbase = (const char*)hag + fr * 512;
  f32x4 zero = {0.f, 0.f, 0.f, 0.f};

  // L1: hag = qt @ Wm2 + S*bm2
  {
    f32x4 acc[4] = {zero, zero, zero, zero};
    #pragma unroll
    for (int kt = 0; kt < 8; ++kt){
      bf16x8 a = *(const bf16x8*)(qbase + (((kl + kt * 32) * 2) ^ swA));
      #pragma unroll
      for (int n = 0; n < 4; ++n){
        bf16x8 b = *(const bf16x8*)(pWm2 + (size_t)(nt0 + n) * 4096 + kt * 512 + lane * 8);
        acc[n] = __builtin_amdgcn_mfma_f32_16x16x32_bf16(a, b, acc[n], 0, 0, 0);
      }
    }
    #pragma unroll
    for (int n = 0; n < 4; ++n){
      int cc = (nt0 + n) * 16 + fr;
      float bv = bm2[cc];
      #pragma unroll
      for (int j = 0; j < 4; ++j){
        int rr = rq + j;
        float v = acc[n][j] + Sl[rr] * bv;
        *(ushort*)((char*)hag + rr * 512 + ((cc * 2) ^ ((rr & 7) << 4))) = f2b(v);
      }
    }
  }
  __syncthreads();

  // L2: tt(=qt) = relu(Hbf @ Wu1a + hag @ Wu1b + bu1)
  {
    f32x4 acc[4] = {zero, zero, zero, zero};
    const ushort* ap_h = Hbf + (size_t)min(row0 + fr, M - 1) * 256 + kl;
    #pragma unroll
    for (int kt = 0; kt < 8; ++kt){
      bf16x8 a = *(const bf16x8*)(ap_h + kt * 32);
      #pragma unroll
      for (int n = 0; n < 4; ++n){
        bf16x8 b = *(const bf16x8*)(pWu1a + (size_t)(nt0 + n) * 4096 + kt * 512 + lane * 8);
        acc[n] = __builtin_amdgcn_mfma_f32_16x16x32_bf16(a, b, acc[n], 0, 0, 0);
      }
    }
    #pragma unroll
    for (int kt = 0; kt < 8; ++kt){
      bf16x8 a = *(const bf16x8*)(hbase + (((kl + kt * 32) * 2) ^ swA));
      #pragma unroll
      for (int n = 0; n < 4; ++n){
        bf16x8 b = *(const bf16x8*)(pWu1b + (size_t)(nt0 + n) * 4096 + kt * 512 + lane * 8);
        acc[n] = __builtin_amdgcn_mfma_f32_16x16x32_bf16(a, b, acc[n], 0, 0, 0);
      }
    }
    __syncthreads();                 // everyone done reading qt (L1) -> reuse as tt
    #pragma unroll
    for (int n = 0; n < 4; ++n){
      int cc = (nt0 + n) * 16 + fr;
      float bv = bu1[cc];
      #pragma unroll
      for (int j = 0; j < 4; ++j){
        int rr = rq + j;
        float v = fmaxf(acc[n][j] + bv, 0.f);
        *(ushort*)((char*)qt + rr * 512 + ((cc * 2) ^ ((rr & 7) << 4))) = f2b(v);
      }
    }
  }
  __syncthreads();

  // L3: out = h + tt @ Wu2 + bu2   (tt lives in qt)
  {
    f32x4 acc[4] = {zero, zero, zero, zero};
    #pragma unroll
    for (int kt = 0; kt < 8; ++kt){
      bf16x8 a = *(const bf16x8*)(qbase + (((kl + kt * 32) * 2) ^ swA));
      #pragma unroll
      for (int n = 0; n < 4; ++n){
        bf16x8 b = *(const bf16x8*)(pWu2 + (size_t)(nt0 + n) * 4096 + kt * 512 + lane * 8);
        acc[n] = __builtin_amdgcn_mfma_f32_16x16x32_bf16(a, b, acc[n], 0, 0, 0);
      }
    }
    #pragma unroll
    for (int n = 0; n < 4; ++n){
      int cc = (nt0 + n) * 16 + fr;
      float bv = bu2[cc];
      #pragma unroll
      for (int j = 0; j < 4; ++j){
        int gr = row0 + rq + j;
        if (gr < M)
          out[(size_t)gr * 256 + cc] = acc[n][j] + bv + h[(size_t)gr * 256 + cc];
      }
    }
  }
}

extern "C" void kernel_launch(void* const* d_in, const int* in_sizes, int n_in,
                              void* d_out, int out_size, void* d_ws, size_t ws_size,
                              hipStream_t stream){
  const float* h   = (const float*)d_in[0];
  const int*   ei  = (const int*)d_in[1];
  const int*   val = (const int*)d_in[3];
  const float* Wm1 = (const float*)d_in[4];
  const float* bm1 = (const float*)d_in[5];
  const float* Wm2 = (const float*)d_in[6];
  const float* bm2 = (const float*)d_in[7];
  const float* Wu1 = (const float*)d_in[8];
  const float* bu1 = (const float*)d_in[9];
  const float* Wu2 = (const float*)d_in[10];
  const float* bu2 = (const float*)d_in[11];
  const float* Wa1 = (const float*)d_in[12];
  const float* ba1 = (const float*)d_in[13];
  const float* Wa2 = (const float*)d_in[14];
  const float* ba2 = (const float*)d_in[15];
  int N = in_sizes[0] / D;
  int E = in_sizes[1] / 2;
  float* out = (float*)d_out;

  char* ws = (char*)d_ws;
  size_t o = 0;
  auto alloc = [&](size_t bytes)->char*{
    char* p = ws + o; o += (bytes + 255) & ~(size_t)255; return p;
  };
  float*  P1    = (float*) alloc((size_t)N * D * 4);
  ushort* P2    = (ushort*)alloc((size_t)N * D * 2);
  ushort* Hbf   = (ushort*)alloc((size_t)N * D * 2);
  int*    cur   = (int*)   alloc((size_t)N * 4);
  uint2*  elist = (uint2*) alloc((size_t)N * CAP * 8);
  ushort* pAll  = (ushort*)alloc((size_t)6 * 65536 * 2);
  ushort* pWm1c = pAll;               // [Wm1a|Wm1b] (N=512 cat)
  ushort* pWm2  = pAll + 2 * 65536;
  ushort* pWu1a = pAll + 3 * 65536;
  ushort* pWu1b = pAll + 4 * 65536;
  ushort* pWu2  = pAll + 5 * 65536;

  int NC = N * D;
  prep_kernel<<<2048, 256, 0, stream>>>(h, Hbf, NC, Wm1, Wm2, Wu1, Wu2, pAll, cur, N);

  int mblocks = (N + 127) / 128;

  // D2: G1 (split P1|P2) + edge bucketing
  g1f_kernel<<<1024, 256, 32768, stream>>>(
      Hbf, pWm1c, P1, P2, ei, val, Wa1, ba1, Wa2, ba2, cur, elist,
      N, E, mblocks * 8);

  // D3: fused aggregation + row-local 3-layer tail (proven v2)
  fused_tail_kernel<<<(N + TBM - 1) / TBM, 256, 0, stream>>>(
      P1, P2, cur, elist, val, Wm1, bm1, Hbf,
      pWm2, pWu1a, pWu1b, pWu2, bm2, bu1, bu2, h, out, N);
}